// Round 1
// baseline (191.170 us; speedup 1.0000x reference)
//
#include <hip/hip_runtime.h>
#include <hip/hip_bf16.h>
#include <math.h>

typedef __bf16 bf16x8 __attribute__((ext_vector_type(8)));
typedef float f32x4 __attribute__((ext_vector_type(4)));
typedef unsigned short u16x8 __attribute__((ext_vector_type(8)));
typedef unsigned short u16;

#define S_LEN 2048
#define DMODEL 1024
#define NH 16

__device__ __forceinline__ u16 f2bf(float f) {
    __bf16 b = (__bf16)f;
    return __builtin_bit_cast(u16, b);
}
__device__ __forceinline__ float bf2f(u16 u) {
    union { unsigned int i; float f; } v; v.i = ((unsigned int)u) << 16; return v.f;
}

// ---------- X f32 -> bf16 (straight copy) ----------
__global__ __launch_bounds__(256) void cvt_x(const float* __restrict__ in, u16* __restrict__ outp) {
    int i = (blockIdx.x * 256 + threadIdx.x) * 4;
    float4 v = *(const float4*)(in + i);
    outp[i + 0] = f2bf(v.x); outp[i + 1] = f2bf(v.y);
    outp[i + 2] = f2bf(v.z); outp[i + 3] = f2bf(v.w);
}

// ---------- W [1024][3072] f32 -> Wt [3072][1024] bf16 (tiled transpose) ----------
__global__ __launch_bounds__(256) void transpose_w(const float* __restrict__ W, u16* __restrict__ Wt) {
    __shared__ u16 tile[32][33];  // +1 pad: conflict-free column reads
    int n0 = blockIdx.x * 32, k0 = blockIdx.y * 32;
    int tx = threadIdx.x & 31, ty = threadIdx.x >> 5;
#pragma unroll
    for (int i = 0; i < 4; i++) {
        int k = ty + i * 8;
        tile[k][tx] = f2bf(W[(size_t)(k0 + k) * 3072 + n0 + tx]);
    }
    __syncthreads();
#pragma unroll
    for (int i = 0; i < 4; i++) {
        int n = ty + i * 8;
        Wt[(size_t)(n0 + n) * 1024 + k0 + tx] = tile[tx][n];
    }
}

// ---------- QKV GEMM: C[4096][3072] = Xb[4096][1024] @ Wt[3072][1024]^T, bf16 MFMA ----------
// 128x128 tile, BK=64, 4 waves (2x2), each wave 64x64 = 4x4 frags of 16x16x32.
// LDS rows are 128B; XOR swizzle chunk ^= (row&7) for conflict-free ds_read_b128.
__global__ __launch_bounds__(256) void qkv_gemm(const u16* __restrict__ A, const u16* __restrict__ Bt,
                                                u16* __restrict__ C) {
    __shared__ alignas(16) u16 As[128 * 64];
    __shared__ alignas(16) u16 Bs[128 * 64];
    const int tid = threadIdx.x, l = tid & 63, w = tid >> 6;
    const int bm = blockIdx.y, bn = blockIdx.x;
    const int wm = w >> 1, wn = w & 1;
    const int c0 = l & 15, g = l >> 4;
    f32x4 acc[4][4] = {};
    for (int kt = 0; kt < 1024; kt += 64) {
        __syncthreads();
#pragma unroll
        for (int n = 0; n < 4; n++) {  // 1024 chunks of 16B per tile, 4 per thread
            int i = tid + n * 256;
            int r = i >> 3, c = i & 7;
            u16x8 va = *(const u16x8*)(A + (size_t)(bm * 128 + r) * 1024 + kt + c * 8);
            *(u16x8*)((char*)As + r * 128 + ((c ^ (r & 7)) << 4)) = va;
            u16x8 vb = *(const u16x8*)(Bt + (size_t)(bn * 128 + r) * 1024 + kt + c * 8);
            *(u16x8*)((char*)Bs + r * 128 + ((c ^ (r & 7)) << 4)) = vb;
        }
        __syncthreads();
#pragma unroll
        for (int kk = 0; kk < 2; kk++) {
            bf16x8 af[4], bfr[4];
#pragma unroll
            for (int m = 0; m < 4; m++) {
                int row = wm * 64 + m * 16 + c0;
                af[m] = *(const bf16x8*)((const char*)As + row * 128 + (((g + kk * 4) ^ (row & 7)) << 4));
            }
#pragma unroll
            for (int n = 0; n < 4; n++) {
                int row = wn * 64 + n * 16 + c0;
                bfr[n] = *(const bf16x8*)((const char*)Bs + row * 128 + (((g + kk * 4) ^ (row & 7)) << 4));
            }
#pragma unroll
            for (int m = 0; m < 4; m++)
#pragma unroll
                for (int n = 0; n < 4; n++)
                    acc[m][n] = __builtin_amdgcn_mfma_f32_16x16x32_bf16(af[m], bfr[n], acc[m][n], 0, 0, 0);
        }
    }
    // C/D layout: col = lane&15, row = 4*(lane>>4)+j
#pragma unroll
    for (int m = 0; m < 4; m++)
#pragma unroll
        for (int n = 0; n < 4; n++)
#pragma unroll
            for (int j = 0; j < 4; j++) {
                int row = bm * 128 + wm * 64 + m * 16 + 4 * g + j;
                int col = bn * 128 + wn * 64 + n * 16 + c0;
                C[(size_t)row * 3072 + col] = f2bf(acc[m][n][j]);
            }
}

// ---------- Flash attention: 1 block = (b,h, 64 q-rows), 4 waves x 16 rows, KV tiles of 64 ----------
__global__ __launch_bounds__(256) void attn(const u16* __restrict__ QKV, float* __restrict__ out) {
    __shared__ alignas(16) u16 Ks[64 * 64];      // [key][d], swizzled chunk^=(key&7)
    __shared__ alignas(16) u16 Vt[64 * 64];      // [d][key], swizzled chunk^=(d&7)^((d>>3)&7)
    __shared__ alignas(16) u16 Ps[4][16 * 64];   // per-wave P, [q][key], swizzled chunk^=(q&7)
    const int tid = threadIdx.x, l = tid & 63, w = tid >> 6;
    const int qt = blockIdx.x & 31, bh = blockIdx.x >> 5;
    const int b = bh >> 4, h = bh & 15;
    const u16* base = QKV + (size_t)b * S_LEN * 3072 + h * 64;
    const int c0 = l & 15, g = l >> 4;

    // Q fragments, scale 1/8 folded in (exact: power of 2)
    bf16x8 qf[2];
    {
        int qrow = qt * 64 + w * 16 + c0;
#pragma unroll
        for (int kk = 0; kk < 2; kk++) {
            u16x8 v = *(const u16x8*)(base + (size_t)qrow * 3072 + kk * 32 + g * 8);
            bf16x8 q;
#pragma unroll
            for (int j = 0; j < 8; j++) q[j] = (__bf16)(bf2f(v[j]) * 0.125f);
            qf[kk] = q;
        }
    }
    float m_r[4], l_r[4];
    f32x4 accO[4] = {};
#pragma unroll
    for (int j = 0; j < 4; j++) { m_r[j] = -INFINITY; l_r[j] = 0.f; }

    for (int kv = 0; kv < S_LEN; kv += 64) {
        __syncthreads();  // previous tile fully consumed
#pragma unroll
        for (int n = 0; n < 2; n++) {  // 512 chunks of 16B per operand, 2 per thread
            int i = tid + n * 256;
            int key = i >> 3, c = i & 7;
            const u16* rowp = base + (size_t)(kv + key) * 3072;
            u16x8 vk = *(const u16x8*)(rowp + 1024 + c * 8);
            *(u16x8*)((char*)Ks + key * 128 + ((c ^ (key & 7)) << 4)) = vk;
            u16x8 vv = *(const u16x8*)(rowp + 2048 + c * 8);
#pragma unroll
            for (int j = 0; j < 8; j++) {  // transposed scatter; swizzle makes writes ~conflict-free
                int d = c * 8 + j;
                int slot = (d & 7) ^ ((d >> 3) & 7);
                *(u16*)((char*)Vt + d * 128 + ((key * 2) ^ (slot << 4))) = vv[j];
            }
        }
        __syncthreads();

        // QK^T: sc[kb] covers keys kb*16..+15; C row = 4g+j (q), col = key
        f32x4 sc[4] = {};
#pragma unroll
        for (int kb = 0; kb < 4; kb++) {
            int key = kb * 16 + c0;
#pragma unroll
            for (int kk = 0; kk < 2; kk++) {
                bf16x8 kf = *(const bf16x8*)((const char*)Ks + key * 128 + (((g + kk * 4) ^ (key & 7)) << 4));
                sc[kb] = __builtin_amdgcn_mfma_f32_16x16x32_bf16(qf[kk], kf, sc[kb], 0, 0, 0);
            }
        }
        // online softmax (wave-parallel: 16-lane shfl reduce per row group)
        float alpha[4], mnew[4], psum[4];
#pragma unroll
        for (int j = 0; j < 4; j++) {
            float mx = fmaxf(fmaxf(sc[0][j], sc[1][j]), fmaxf(sc[2][j], sc[3][j]));
            mx = fmaxf(mx, __shfl_xor(mx, 1));
            mx = fmaxf(mx, __shfl_xor(mx, 2));
            mx = fmaxf(mx, __shfl_xor(mx, 4));
            mx = fmaxf(mx, __shfl_xor(mx, 8));
            mnew[j] = fmaxf(m_r[j], mx);
            alpha[j] = __expf(m_r[j] - mnew[j]);
            psum[j] = 0.f;
        }
#pragma unroll
        for (int kb = 0; kb < 4; kb++)
#pragma unroll
            for (int j = 0; j < 4; j++) {
                float p = __expf(sc[kb][j] - mnew[j]);
                sc[kb][j] = p;
                psum[j] += p;
            }
#pragma unroll
        for (int j = 0; j < 4; j++) {
            float s = psum[j];
            s += __shfl_xor(s, 1);
            s += __shfl_xor(s, 2);
            s += __shfl_xor(s, 4);
            s += __shfl_xor(s, 8);
            l_r[j] = l_r[j] * alpha[j] + s;
            m_r[j] = mnew[j];
        }
#pragma unroll
        for (int n = 0; n < 4; n++)
#pragma unroll
            for (int j = 0; j < 4; j++) accO[n][j] *= alpha[j];

        // P -> per-wave LDS (C-layout -> A-layout round trip)
#pragma unroll
        for (int kb = 0; kb < 4; kb++)
#pragma unroll
            for (int j = 0; j < 4; j++) {
                int row = 4 * g + j, key = kb * 16 + c0;
                *(u16*)((char*)Ps[w] + row * 128 + ((key * 2) ^ ((row & 7) << 4))) = f2bf(sc[kb][j]);
            }
        // PV: A = P[16q x 64key], B = V[64key x 64d] read from Vt
#pragma unroll
        for (int kk = 0; kk < 2; kk++) {
            bf16x8 pf = *(const bf16x8*)((const char*)Ps[w] + c0 * 128 + (((g + kk * 4) ^ (c0 & 7)) << 4));
#pragma unroll
            for (int n = 0; n < 4; n++) {
                int d = n * 16 + c0;
                int slot = (d & 7) ^ ((d >> 3) & 7);
                bf16x8 vf = *(const bf16x8*)((const char*)Vt + d * 128 + (((g + kk * 4) ^ slot) << 4));
                accO[n] = __builtin_amdgcn_mfma_f32_16x16x32_bf16(pf, vf, accO[n], 0, 0, 0);
            }
        }
    }
    // epilogue: O / l, f32 out
#pragma unroll
    for (int j = 0; j < 4; j++) {
        float inv = 1.0f / l_r[j];
        int row = qt * 64 + w * 16 + 4 * g + j;
#pragma unroll
        for (int n = 0; n < 4; n++) {
            out[((size_t)b * S_LEN + row) * DMODEL + h * 64 + n * 16 + c0] = accO[n][j] * inv;
        }
    }
}

extern "C" void kernel_launch(void* const* d_in, const int* in_sizes, int n_in,
                              void* d_out, int out_size, void* d_ws, size_t ws_size,
                              hipStream_t stream) {
    const float* X = (const float*)d_in[0];   // [2,2048,1024] f32
    const float* W = (const float*)d_in[1];   // [1024,3072] f32
    float* out = (float*)d_out;               // [2,2048,1024] f32

    u16* Xb  = (u16*)d_ws;                    // 4096*1024 bf16 (8.4 MB)
    u16* Wt  = Xb + (size_t)4096 * 1024;      // 3072*1024 bf16 (6.3 MB)
    u16* QKV = Wt + (size_t)3072 * 1024;      // 4096*3072 bf16 (25.2 MB) — ws total ~40 MB

    cvt_x<<<4096, 256, 0, stream>>>(X, Xb);
    transpose_w<<<dim3(96, 32), 256, 0, stream>>>(W, Wt);
    qkv_gemm<<<dim3(24, 32), 256, 0, stream>>>(Xb, Wt, QKV);
    attn<<<1024, 256, 0, stream>>>(QKV, out);
}